// Round 17
// baseline (3026.101 us; speedup 1.0000x reference)
//
#include <hip/hip_runtime.h>
#include <math.h>

typedef unsigned long long U64;
#define CCAP 4096

__constant__ float cANCH[180] = {
  -18.0f,-8.0f,25.0f,15.0f, -23.7183f,-11.1191f,30.7183f,18.1191f, -30.9228f,-15.0488f,37.9228f,22.0488f,
  -12.0f,-12.0f,19.0f,19.0f, -16.1587f,-16.1587f,23.1587f,23.1587f, -21.3984f,-21.3984f,28.3984f,28.3984f,
  -8.0f,-20.0f,15.0f,27.0f, -11.1191f,-26.2381f,18.1191f,33.2381f, -15.0488f,-34.0976f,22.0488f,41.0976f,
  -38.0f,-16.0f,53.0f,31.0f, -49.9564f,-22.2381f,64.9564f,37.2381f, -65.0204f,-30.0976f,80.0204f,45.0976f,
  -24.0f,-24.0f,39.0f,39.0f, -32.3175f,-32.3175f,47.3175f,47.3175f, -42.7968f,-42.7968f,57.7968f,57.7968f,
  -14.0f,-36.0f,29.0f,51.0f, -19.7183f,-47.4365f,34.7183f,62.4365f, -26.9228f,-61.8456f,41.9228f,76.8456f,
  -74.0f,-28.0f,105.0f,59.0f, -97.3929f,-39.4365f,128.3929f,70.4365f, -126.8661f,-53.8456f,157.8661f,84.8456f,
  -48.0f,-48.0f,79.0f,79.0f, -64.6349f,-64.6349f,95.6349f,95.6349f, -85.5937f,-85.5937f,116.5937f,116.5937f,
  -30.0f,-76.0f,61.0f,107.0f, -41.9564f,-99.9127f,72.9564f,130.9127f, -57.0204f,-130.0409f,88.0204f,161.0409f,
  -150.0f,-60.0f,213.0f,123.0f, -197.3056f,-83.9127f,260.3056f,146.9127f, -256.907f,-114.0409f,319.907f,177.0409f,
  -96.0f,-96.0f,159.0f,159.0f, -129.2699f,-129.2699f,192.2699f,192.2699f, -171.1873f,-171.1873f,234.1873f,234.1873f,
  -58.0f,-148.0f,121.0f,211.0f, -81.3929f,-194.7858f,144.3929f,257.7858f, -110.8661f,-253.7322f,173.8661f,316.7322f,
  -298.0f,-116.0f,425.0f,243.0f, -392.0914f,-162.7858f,519.0914f,289.7858f, -510.6392f,-221.7322f,637.6392f,348.7322f,
  -192.0f,-192.0f,319.0f,319.0f, -258.5398f,-258.5398f,385.5398f,385.5398f, -342.3747f,-342.3747f,469.3747f,469.3747f,
  -118.0f,-300.0f,245.0f,427.0f, -165.3056f,-394.6113f,292.3056f,521.6113f, -224.907f,-513.814f,351.907f,640.814f
};

__device__ __constant__ int dH[5]      = {64,32,16,8,4};
__device__ __constant__ int dLogW[5]   = {6,5,4,3,2};
__device__ __constant__ int dHW[5]     = {4096,1024,256,64,16};
__device__ __constant__ int dPW[5]     = {66,34,18,10,6};
__device__ __constant__ int dPS[5]     = {4356,1156,324,100,36};
__device__ __constant__ int dPadOff[5] = {0,2230272,2822144,2988032,3039232};
__device__ __constant__ int dCO[5]     = {0,5898240,7372800,7741440,7833600};
__device__ __constant__ int dBO[5]     = {0,294912,368640,387072,391680};
__device__ __constant__ float dStrF[5] = {8.f,16.f,32.f,64.f,128.f};
// 256-pixel blocks (finals): counts 32,8,2,2,2 -> bases
__device__ __constant__ int dBase[6]   = {0,32,40,42,44,46};
__device__ __constant__ int dNPB[5]    = {16,4,1,1,1};
// 768-pixel blocks (hidden, 3px/thread): counts 12,4,2,2,2 -> bases
__device__ __constant__ int dB3[6]   = {0,12,16,18,20,22};
__device__ __constant__ int dNPB3[5] = {6,2,1,1,1};

// ---------------- utility ----------------
__global__ void fill_zero4(float4* __restrict__ p, int n4) {
  for (int i = blockIdx.x*blockDim.x + threadIdx.x; i < n4; i += gridDim.x*blockDim.x)
    p[i] = make_float4(0.f,0.f,0.f,0.f);
}

// feat (B,256,H,W) -> channel-block-4 padded: P4[b][kq=c/4][vpix][c%4]
__global__ void pad_one_p4(const float* __restrict__ f, float* __restrict__ P,
                           int n, int logHW, int logW, int W, int PW, int PS) {
  const int HW1 = (1<<logHW) - 1;
  for (int i = blockIdx.x*blockDim.x + threadIdx.x; i < n; i += gridDim.x*blockDim.x) {
    const int bc = i >> logHW;
    const int p  = i & HW1;
    const int b = bc >> 8, c = bc & 255;
    const int y = p >> logW, x = p & (W-1);
    const int vpix = (y+1)*PW + (x+1);
    P[(((size_t)(b*64 + (c>>2)))*PS + vpix)*4 + (c&3)] = f[i];
  }
}

// w (Cout,256,3,3) -> wT[tap][k][ocP], zero padded ocs
__global__ void transp_w(const float* __restrict__ w, float* __restrict__ wT,
                         int Cout, int OCP) {
  const int n = 9*256*OCP;
  for (int i = blockIdx.x*blockDim.x + threadIdx.x; i < n; i += gridDim.x*blockDim.x) {
    const int oc = i % OCP;
    const int kt = i / OCP;
    const int k  = kt % 256;
    const int t  = kt / 256;
    wT[i] = (oc < Cout) ? w[(size_t)oc*2304 + k*9 + t] : 0.f;
  }
}

// 4 consecutive k rows x 16 ocs fed by one float4 (k ascending: x,y,z,w)
#define QUAD(KB, Q)                                                     \
  {                                                                     \
    const float* __restrict__ w0 = wp + (size_t)((KB)+0)*OCL;           \
    const float* __restrict__ w1 = wp + (size_t)((KB)+1)*OCL;           \
    const float* __restrict__ w2 = wp + (size_t)((KB)+2)*OCL;           \
    const float* __restrict__ w3 = wp + (size_t)((KB)+3)*OCL;           \
    _Pragma("unroll") for (int o=0;o<16;++o) acc[o]=fmaf(w0[o],(Q).x,acc[o]); \
    _Pragma("unroll") for (int o=0;o<16;++o) acc[o]=fmaf(w1[o],(Q).y,acc[o]); \
    _Pragma("unroll") for (int o=0;o<16;++o) acc[o]=fmaf(w2[o],(Q).z,acc[o]); \
    _Pragma("unroll") for (int o=0;o<16;++o) acc[o]=fmaf(w3[o],(Q).w,acc[o]); \
  }

// same, 3 pixels sharing weight rows; each pixel's chain stays tap-outer, k-ascending
#define QUAD3(KB, QA, QB, QC)                                           \
  {                                                                     \
    const float* __restrict__ w0 = wp + (size_t)((KB)+0)*OCL;           \
    const float* __restrict__ w1 = wp + (size_t)((KB)+1)*OCL;           \
    const float* __restrict__ w2 = wp + (size_t)((KB)+2)*OCL;           \
    const float* __restrict__ w3 = wp + (size_t)((KB)+3)*OCL;           \
    _Pragma("unroll") for (int o=0;o<16;++o) { acc0[o]=fmaf(w0[o],(QA).x,acc0[o]); acc1[o]=fmaf(w0[o],(QB).x,acc1[o]); acc2[o]=fmaf(w0[o],(QC).x,acc2[o]); } \
    _Pragma("unroll") for (int o=0;o<16;++o) { acc0[o]=fmaf(w1[o],(QA).y,acc0[o]); acc1[o]=fmaf(w1[o],(QB).y,acc1[o]); acc2[o]=fmaf(w1[o],(QC).y,acc2[o]); } \
    _Pragma("unroll") for (int o=0;o<16;++o) { acc0[o]=fmaf(w2[o],(QA).z,acc0[o]); acc1[o]=fmaf(w2[o],(QB).z,acc1[o]); acc2[o]=fmaf(w2[o],(QC).z,acc2[o]); } \
    _Pragma("unroll") for (int o=0;o<16;++o) { acc0[o]=fmaf(w3[o],(QA).w,acc0[o]); acc1[o]=fmaf(w3[o],(QB).w,acc1[o]); acc2[o]=fmaf(w3[o],(QC).w,acc2[o]); } \
  }

// ---------------- fused hidden conv (cls+box), 3 pixels/thread ----------
// grid = (24, 32): by>>4 = head, by&15 = oc-block. bx (0..21) -> level/batch/768-px block;
// thread handles pix0 = pb*768+tid, pix1 = pix0+256, pix2 = pix0+512. XCD = bx%8 preserved.
// Per-output fmaf chain identical to round 16 -> bitwise.
__global__ __launch_bounds__(256)
void conv_hidden_fused(const float* __restrict__ srcC, const float* __restrict__ srcB,
                       float* __restrict__ dstC, float* __restrict__ dstB,
                       const float* __restrict__ wTc, const float* __restrict__ wTb,
                       const float* __restrict__ biasC, const float* __restrict__ biasB)
{
  const int OCL = 256;
  const int bx = blockIdx.x;
  if (bx >= 22) return;
  int l = 0;
  if (bx >= dB3[1]) l = 1;
  if (bx >= dB3[2]) l = 2;
  if (bx >= dB3[3]) l = 3;
  if (bx >= dB3[4]) l = 4;
  const int npb = dNPB3[l];
  const int rel = bx - dB3[l];
  const int b = rel / npb, pb = rel % npb;
  const int W = dH[l], logW = dLogW[l], HW = dHW[l], PW = dPW[l], PS = dPS[l];
  const int tid = threadIdx.x;
  const int pix0 = pb*768 + tid;
  const int pix1 = pix0 + 256;
  const int pix2 = pix0 + 512;
  if (pix0 >= HW) return;
  const bool a1 = pix1 < HW, a2 = pix2 < HW;
  const int y0 = pix0 >> logW, x0 = pix0 & (W-1);
  const int y1 = pix1 >> logW, x1 = pix1 & (W-1);
  const int y2 = pix2 >> logW, x2 = pix2 & (W-1);
  const int voff0 = (y0+1)*PW + (x0+1);
  const int voff1 = a1 ? (y1+1)*PW + (x1+1) : voff0;
  const int voff2 = a2 ? (y2+1)*PW + (x2+1) : voff0;
  const int head = blockIdx.y >> 4;
  const float* __restrict__ IN  = head ? srcB : srcC;
  float* __restrict__ OUT       = head ? dstB : dstC;
  const float* __restrict__ wT  = head ? wTb : wTc;
  const float* __restrict__ bias= head ? biasB : biasC;
  const float4* __restrict__ P4 = (const float4*)(IN + dPadOff[l]);
  const float4* __restrict__ inB = P4 + (size_t)b*64*PS;
  const int oc0 = (blockIdx.y & 15) * 16;
  float acc0[16], acc1[16], acc2[16];
#pragma unroll
  for (int o = 0; o < 16; ++o) { acc0[o] = 0.f; acc1[o] = 0.f; acc2[o] = 0.f; }
#pragma unroll 1
  for (int t = 0; t < 9; ++t) {
    const int dy = t / 3, dx = t - dy * 3;
    const int sh = (dy-1)*PW + (dx-1);
    const float4* __restrict__ ipA = inB + (voff0 + sh);
    const float4* __restrict__ ipB = inB + (voff1 + sh);
    const float4* __restrict__ ipC = inB + (voff2 + sh);
    const float* __restrict__ wp = wT + (size_t)t*256*OCL + oc0;
#pragma unroll 1
    for (int k0 = 0; k0 < 256; k0 += 16) {
      const int kq = k0 >> 2;
      const float4 qa0 = ipA[(size_t)(kq+0)*PS];
      const float4 qb0 = ipB[(size_t)(kq+0)*PS];
      const float4 qc0 = ipC[(size_t)(kq+0)*PS];
      const float4 qa1 = ipA[(size_t)(kq+1)*PS];
      const float4 qb1 = ipB[(size_t)(kq+1)*PS];
      const float4 qc1 = ipC[(size_t)(kq+1)*PS];
      const float4 qa2 = ipA[(size_t)(kq+2)*PS];
      const float4 qb2 = ipB[(size_t)(kq+2)*PS];
      const float4 qc2 = ipC[(size_t)(kq+2)*PS];
      const float4 qa3 = ipA[(size_t)(kq+3)*PS];
      const float4 qb3 = ipB[(size_t)(kq+3)*PS];
      const float4 qc3 = ipC[(size_t)(kq+3)*PS];
      QUAD3(k0+ 0, qa0, qb0, qc0);
      QUAD3(k0+ 4, qa1, qb1, qc1);
      QUAD3(k0+ 8, qa2, qb2, qc2);
      QUAD3(k0+12, qa3, qb3, qc3);
    }
  }
  float4* __restrict__ O4 = (float4*)(OUT + dPadOff[l]);
  float4* __restrict__ opBase = O4 + ((size_t)b*64 + (oc0 >> 2))*PS;
#pragma unroll
  for (int j = 0; j < 4; ++j) {
    const float b0 = bias[oc0+4*j+0], b1 = bias[oc0+4*j+1];
    const float b2 = bias[oc0+4*j+2], b3 = bias[oc0+4*j+3];
    opBase[(size_t)j*PS + voff0] = make_float4(
      fmaxf(acc0[4*j+0] + b0, 0.f), fmaxf(acc0[4*j+1] + b1, 0.f),
      fmaxf(acc0[4*j+2] + b2, 0.f), fmaxf(acc0[4*j+3] + b3, 0.f));
    if (a1)
      opBase[(size_t)j*PS + voff1] = make_float4(
        fmaxf(acc1[4*j+0] + b0, 0.f), fmaxf(acc1[4*j+1] + b1, 0.f),
        fmaxf(acc1[4*j+2] + b2, 0.f), fmaxf(acc1[4*j+3] + b3, 0.f));
    if (a2)
      opBase[(size_t)j*PS + voff2] = make_float4(
        fmaxf(acc2[4*j+0] + b0, 0.f), fmaxf(acc2[4*j+1] + b1, 0.f),
        fmaxf(acc2[4*j+2] + b2, 0.f), fmaxf(acc2[4*j+3] + b3, 0.f));
  }
}

// ---------------- fused finals, 1 pixel/thread (round-14/16 winner) ----------------
// grid = (48, 48): by<45 -> cls oc-block (sigmoid, Cout=720, OCL=720); else box (Cout=36, OCL=48)
__global__ __launch_bounds__(256)
void conv_final_fused(const float* __restrict__ srcC, const float* __restrict__ srcB,
                      float* __restrict__ clsm, float* __restrict__ boxm,
                      const float* __restrict__ wTfc, const float* __restrict__ wTfb,
                      const float* __restrict__ biasC, const float* __restrict__ biasB)
{
  const int bx = blockIdx.x;
  if (bx >= 46) return;
  int l = 0;
  if (bx >= dBase[1]) l = 1;
  if (bx >= dBase[2]) l = 2;
  if (bx >= dBase[3]) l = 3;
  if (bx >= dBase[4]) l = 4;
  const int npb = dNPB[l];
  const int rel = bx - dBase[l];
  const int b = rel / npb, pb = rel % npb;
  const int W = dH[l], logW = dLogW[l], HW = dHW[l], PW = dPW[l], PS = dPS[l];
  const int pix = pb*256 + threadIdx.x;
  if (pix >= HW) return;
  const bool isCls = blockIdx.y < 45;
  const int ocb = isCls ? blockIdx.y : (blockIdx.y - 45);
  const int OCL = isCls ? 720 : 48;
  const int Cout = isCls ? 720 : 36;
  const float* __restrict__ IN  = isCls ? srcC : srcB;
  const float* __restrict__ wT  = isCls ? wTfc : wTfb;
  const float* __restrict__ bias= isCls ? biasC : biasB;
  const int y = pix >> logW, x = pix & (W-1);
  const int voff = (y+1)*PW + (x+1);
  const float4* __restrict__ P4 = (const float4*)(IN + dPadOff[l]);
  const float4* __restrict__ inB = P4 + (size_t)b*64*PS + voff;
  const int oc0 = ocb * 16;
  float acc[16];
#pragma unroll
  for (int o = 0; o < 16; ++o) acc[o] = 0.f;
#pragma unroll 1
  for (int t = 0; t < 9; ++t) {
    const int dy = t / 3, dx = t - dy * 3;
    const float4* __restrict__ ip = inB + ((dy-1)*PW + (dx-1));
    const float* __restrict__ wp = wT + (size_t)t*256*OCL + oc0;
#pragma unroll 1
    for (int k0 = 0; k0 < 256; k0 += 16) {
      const int kq = k0 >> 2;
      const float4 q0 = ip[(size_t)(kq+0)*PS];
      const float4 q1 = ip[(size_t)(kq+1)*PS];
      const float4 q2 = ip[(size_t)(kq+2)*PS];
      const float4 q3 = ip[(size_t)(kq+3)*PS];
      QUAD(k0+ 0, q0);
      QUAD(k0+ 4, q1);
      QUAD(k0+ 8, q2);
      QUAD(k0+12, q3);
    }
  }
  const int outOff = isCls ? dCO[l] : dBO[l];
  float* __restrict__ OUT = isCls ? clsm : boxm;
#pragma unroll
  for (int o = 0; o < 16; ++o) {
    const int oc = oc0 + o;
    if (oc < Cout) {
      float tv = acc[o] + bias[oc];
      if (isCls) tv = 1.f / (1.f + expf(-tv));
      OUT[(size_t)outOff + ((size_t)b*Cout + oc)*HW + pix] = tv;
    }
  }
}

// ---------------- exact top-1000 per (batch,level) ----------------
__global__ void topk_init(unsigned* __restrict__ hist, unsigned* __restrict__ state) {
  for (int i = threadIdx.x; i < 2560; i += blockDim.x) hist[i] = 0u;
  if (threadIdx.x < 10) {
    state[threadIdx.x*4+0] = 0u; state[threadIdx.x*4+1] = 1000u;
    state[threadIdx.x*4+2] = 0u; state[threadIdx.x*4+3] = 0u;
  }
}

__global__ void topk_hist(const float* __restrict__ clsm, unsigned* __restrict__ hist,
                          const unsigned* __restrict__ state, int pass)
{
  __shared__ unsigned lh[256];
  const int id = blockIdx.y, l = id % 5, b = id / 5;
  const int N = 720 * dHW[l];
  const float* __restrict__ sp = clsm + dCO[l] + (size_t)b*720*dHW[l];
  for (int i = threadIdx.x; i < 256; i += blockDim.x) lh[i] = 0u;
  __syncthreads();
  const unsigned prefix = state[id*4];
  for (int i = blockIdx.x*blockDim.x + threadIdx.x; i < N; i += gridDim.x*blockDim.x) {
    const unsigned bits = __float_as_uint(sp[i]);
    unsigned bin; bool ok;
    if (pass == 0)      { bin = bits >> 24;          ok = true; }
    else if (pass == 1) { bin = (bits >> 16) & 0xFF; ok = ((bits >> 24) == prefix); }
    else                { bin = (bits >>  8) & 0xFF; ok = ((bits >> 16) == prefix); }
    if (ok) atomicAdd(&lh[bin], 1u);
  }
  __syncthreads();
  for (int i = threadIdx.x; i < 256; i += blockDim.x)
    if (lh[i]) atomicAdd(&hist[id*256 + i], lh[i]);
}

__global__ void topk_scan(unsigned* __restrict__ hist, unsigned* __restrict__ state) {
  const int id = threadIdx.x;
  if (id < 10) {
    const unsigned k = state[id*4+1];
    unsigned cum = 0; int d = 255;
    for (; d > 0; --d) {
      const unsigned h = hist[id*256 + d];
      if (cum + h >= k) break;
      cum += h;
    }
    state[id*4+0] = (state[id*4+0] << 8) | (unsigned)d;
    state[id*4+1] = k - cum;
  }
  __syncthreads();
  for (int i = threadIdx.x; i < 2560; i += blockDim.x) hist[i] = 0u;
}

__global__ void topk_compact(const float* __restrict__ clsm, unsigned* __restrict__ state,
                             U64* __restrict__ cbuf)
{
  const int id = blockIdx.y, l = id % 5, b = id / 5;
  const int N = 720 * dHW[l];
  const float* __restrict__ sp = clsm + dCO[l] + (size_t)b*720*dHW[l];
  const unsigned p24 = state[id*4];
  for (int i = blockIdx.x*blockDim.x + threadIdx.x; i < N; i += gridDim.x*blockDim.x) {
    const unsigned bits = __float_as_uint(sp[i]);
    if ((bits >> 8) >= p24) {
      const unsigned pos = atomicAdd(&state[id*4+2], 1u);
      if (pos < CCAP)
        cbuf[(size_t)id*CCAP + pos] = ((U64)bits << 32) | (U64)(0xFFFFFFFFu - (unsigned)i);
    }
  }
}

__global__ __launch_bounds__(1024)
void topk_sort_store(const U64* __restrict__ cbuf, const unsigned* __restrict__ state,
                     float* __restrict__ cand_s, float* __restrict__ cand_c,
                     unsigned* __restrict__ sel)
{
  __shared__ U64 sk[CCAP];
  const int id = blockIdx.x, l = id % 5, b = id / 5;
  const int t = threadIdx.x;
  unsigned M = state[id*4+2]; if (M > (unsigned)CCAP) M = CCAP;
  for (int i = t; i < CCAP; i += 1024) sk[i] = (i < (int)M) ? cbuf[(size_t)id*CCAP + i] : 0ull;
  __syncthreads();
  for (int k = 2; k <= CCAP; k <<= 1)
    for (int j = k >> 1; j > 0; j >>= 1) {
      for (int u = t; u < CCAP/2; u += 1024) {
        const int i1 = ((u & ~(j-1)) << 1) | (u & (j-1));
        const int i2 = i1 + j;
        const bool asc = ((i1 & k) == 0);
        const U64 a = sk[i1], c = sk[i2];
        if ((a < c) == asc) { sk[i1] = c; sk[i2] = a; }
      }
      __syncthreads();
    }
  const int HW = dHW[l];
  for (int j = t; j < 1000; j += 1024) {
    float sc_ = 0.f, cf = 0.f; unsigned sidx = 0xFFFFFFFFu;
    if (j < (int)M) {
      const U64 key = sk[j];
      const float s = __uint_as_float((unsigned)(key >> 32));
      const unsigned idx = 0xFFFFFFFFu - (unsigned)key;
      if (s >= 0.05f) {
        const int ch = (int)(idx / (unsigned)HW);
        const int cls = ch % 80;
        sc_ = s; cf = (float)cls; sidx = idx;
      }
    }
    const int slot = b*5000 + l*1000 + j;
    cand_s[slot] = sc_; cand_c[slot] = cf; sel[slot] = sidx;
  }
}

__global__ __launch_bounds__(1024)
void box_decode(const float* __restrict__ boxm, const float* __restrict__ cand_s,
                const unsigned* __restrict__ sel, float4* __restrict__ cand_b)
{
  const int id = blockIdx.x, l = id % 5, b = id / 5;
  const int HW = dHW[l], W = dH[l], logW = dLogW[l];
  const float stride = dStrF[l];
  const int j = threadIdx.x;
  if (j >= 1000) return;
  const int slot = b*5000 + l*1000 + j;
  float4 bx = make_float4(0.f,0.f,0.f,0.f);
  if (cand_s[slot] > 0.f) {
    const unsigned idx = sel[slot];
    const int pix = (int)(idx & (unsigned)(HW-1));
    const int ch  = (int)(idx >> (2*logW));
    const int a   = ch / 80;
    const int xx = pix & (W-1), yy = pix >> logW;
    const float* __restrict__ bm = boxm + dBO[l] + (size_t)b*36*HW;
    const float d0 = bm[(size_t)(a*4+0)*HW + pix];
    const float d1 = bm[(size_t)(a*4+1)*HW + pix];
    const float d2 = bm[(size_t)(a*4+2)*HW + pix];
    const float d3 = bm[(size_t)(a*4+3)*HW + pix];
    const float* A = &cANCH[l*36 + a*4];
    const float g0 = (float)xx * stride + A[0];
    const float g1 = (float)yy * stride + A[1];
    const float g2 = (float)xx * stride + A[2];
    const float g3 = (float)yy * stride + A[3];
    const float awx = g2 - g0 + 1.f, awy = g3 - g1 + 1.f;
    const float cx = g0 + 0.5f*awx, cy = g1 + 0.5f*awy;
    const float pcx = d0*awx + cx, pcy = d1*awy + cy;
    const float pwx = expf(d2)*awx, pwy = expf(d3)*awy;
    const float Mx = (float)W*stride - 1.f, My = (float)W*stride - 1.f;
    const float x1 = fminf(fmaxf(pcx - 0.5f*pwx, 0.f), Mx);
    const float y1 = fminf(fmaxf(pcy - 0.5f*pwy, 0.f), My);
    const float x2 = fminf(fmaxf(pcx + 0.5f*pwx - 1.f, 0.f), Mx);
    const float y2 = fminf(fmaxf(pcy + 0.5f*pwy - 1.f, 0.f), My);
    bx = make_float4(x1, y1, x2, y2);
  }
  cand_b[slot] = bx;
}

// ---------------- NMS ----------------
__global__ __launch_bounds__(1024)
void nms_sort(const float* __restrict__ cs, const float4* __restrict__ cb, const float* __restrict__ cc,
              float* __restrict__ ss, float4* __restrict__ sb, float* __restrict__ sc)
{
  extern __shared__ U64 sk[];
  const int b = blockIdx.x;
  const int t = threadIdx.x;
  for (int i = t; i < 8192; i += 1024) {
    U64 key = 0ull;
    if (i < 5000) {
      const unsigned bits = __float_as_uint(cs[b*5000 + i]);
      key = ((U64)bits << 32) | (U64)(0xFFFFFFFFu - (unsigned)i);
    }
    sk[i] = key;
  }
  __syncthreads();
  for (int k = 2; k <= 8192; k <<= 1)
    for (int j = k >> 1; j > 0; j >>= 1) {
      for (int u = t; u < 4096; u += 1024) {
        const int i1 = ((u & ~(j-1)) << 1) | (u & (j-1));
        const int i2 = i1 + j;
        const bool asc = ((i1 & k) == 0);
        const U64 a = sk[i1], c = sk[i2];
        if ((a < c) == asc) { sk[i1] = c; sk[i2] = a; }
      }
      __syncthreads();
    }
  for (int i = t; i < 5000; i += 1024) {
    const unsigned pos = 0xFFFFFFFFu - (unsigned)sk[i];
    ss[b*5008 + i] = cs[b*5000 + pos];
    sb[b*5008 + i] = cb[b*5000 + pos];
    sc[b*5008 + i] = cc[b*5000 + pos];
  }
}

__global__ __launch_bounds__(1024)
void nms_greedy(const float* __restrict__ ss, const float4* __restrict__ sb, const float* __restrict__ sc,
                float* __restrict__ outp)
{
  const int b = blockIdx.x;
  const int t = threadIdx.x;
  __shared__ int red[16];
  __shared__ int selSh;
  __shared__ float bc[8];

  const float* SS = ss + (size_t)b*5008;
  const float4* SB = sb + (size_t)b*5008;
  const float* SC = sc + (size_t)b*5008;

  float s[5], c[5], ar[5]; float4 bx[5]; bool val[5];
#pragma unroll
  for (int k = 0; k < 5; ++k) {
    const int j = t + k*1024;
    if (j < 5000) {
      s[k] = SS[j]; c[k] = SC[j]; bx[k] = SB[j];
      val[k] = (s[k] > 0.f);
      ar[k] = (bx[k].z - bx[k].x + 1.f) * (bx[k].w - bx[k].y + 1.f);
    } else {
      s[k] = 0.f; c[k] = 0.f; bx[k] = make_float4(0.f,0.f,0.f,0.f);
      val[k] = false; ar[k] = 1.f;
    }
  }

  for (int i = 0; i < 100; ++i) {
    int loc = 0x7FFFFFFF;
#pragma unroll
    for (int k = 0; k < 5; ++k) if (val[k]) { const int j = t + k*1024; loc = (j < loc) ? j : loc; }
    for (int off = 32; off > 0; off >>= 1) { const int o = __shfl_down(loc, off); loc = (o < loc) ? o : loc; }
    if ((t & 63) == 0) red[t >> 6] = loc;
    __syncthreads();
    if (t < 64) {
      int v = (t < 16) ? red[t] : 0x7FFFFFFF;
      for (int off = 8; off > 0; off >>= 1) { const int o = __shfl_down(v, off); v = (o < v) ? o : v; }
      if (t == 0) selSh = v;
    }
    __syncthreads();
    const int sel_ = selSh;
    if (sel_ == 0x7FFFFFFF) {
      if (t == 0) {
        outp[b*100 + i] = 0.f;
        outp[200 + (b*100 + i)*4 + 0] = 0.f;
        outp[200 + (b*100 + i)*4 + 1] = 0.f;
        outp[200 + (b*100 + i)*4 + 2] = 0.f;
        outp[200 + (b*100 + i)*4 + 3] = 0.f;
        outp[1000 + b*100 + i] = 0.f;
      }
    } else {
      if (t == (sel_ & 1023)) {
        const int k = sel_ >> 10;
        bc[0] = s[k]; bc[1] = c[k];
        bc[2] = bx[k].x; bc[3] = bx[k].y; bc[4] = bx[k].z; bc[5] = bx[k].w;
        bc[6] = ar[k];
        outp[b*100 + i] = s[k];
        outp[200 + (b*100 + i)*4 + 0] = bx[k].x;
        outp[200 + (b*100 + i)*4 + 1] = bx[k].y;
        outp[200 + (b*100 + i)*4 + 2] = bx[k].z;
        outp[200 + (b*100 + i)*4 + 3] = bx[k].w;
        outp[1000 + b*100 + i] = c[k];
      }
      __syncthreads();
      const float si = bc[0], ci = bc[1], ai = bc[6];
      const float bix = bc[2], biy = bc[3], biz = bc[4], biw = bc[5];
#pragma unroll
      for (int k = 0; k < 5; ++k) {
        if (!val[k]) continue;
        const float xx1 = fmaxf(bx[k].x, bix), yy1 = fmaxf(bx[k].y, biy);
        const float xx2 = fminf(bx[k].z, biz), yy2 = fminf(bx[k].w, biw);
        const float iw = fmaxf(xx2 - xx1 + 1.f, 0.f), ih = fmaxf(yy2 - yy1 + 1.f, 0.f);
        const float inter = iw * ih;
        const float iou = inter / (ar[k] + ai - inter);
        if (s[k] <= si && iou > 0.5f && c[k] == ci) val[k] = false;
      }
    }
    __syncthreads();
  }
}

// ---------------- host ----------------
extern "C" void kernel_launch(void* const* d_in, const int* in_sizes, int n_in,
                              void* d_out, int out_size, void* d_ws, size_t ws_size,
                              hipStream_t stream)
{
  (void)in_sizes; (void)n_in; (void)out_size; (void)ws_size;
  const float* feat[5]; const float* cwp[5]; const float* cbp[5]; const float* bwp[5]; const float* bbp[5];
  for (int i = 0; i < 5; ++i) feat[i] = (const float*)d_in[i];
  for (int i = 0; i < 5; ++i) {
    cwp[i] = (const float*)d_in[5 + 4*i + 0];
    cbp[i] = (const float*)d_in[5 + 4*i + 1];
    bwp[i] = (const float*)d_in[5 + 4*i + 2];
    bbp[i] = (const float*)d_in[5 + 4*i + 3];
  }

  float* ws = (float*)d_ws;
  const size_t BUFSZ = 3057664;
  float* P     = ws;
  float* Ac    = ws + BUFSZ;
  float* Bc    = ws + 2*BUFSZ;
  float* Ab    = ws + 3*BUFSZ;
  float* Bb    = ws + 4*BUFSZ;
  float* clsm  = ws + 5*BUFSZ;
  float* boxm  = clsm + 7856640;
  float* wreg  = boxm + 392832;
  float* wTc   = wreg;
  float* wTb   = wreg + 589824;
  float* wTfc  = wreg;
  float* wTfb  = wreg + 1658880;
  float* cand_s = wreg + 1769472;
  float* cand_b = cand_s + 10000;
  float* cand_c = cand_b + 40000;
  float* srt_s  = cand_c + 10000;
  float* srt_b  = srt_s + 10016;
  float* srt_c  = srt_b + 40064;
  unsigned* sel   = (unsigned*)(srt_c + 10016);
  unsigned* hist  = (unsigned*)(srt_c + 20016);
  unsigned* state = (unsigned*)(srt_c + 22576);
  U64*      cbuf  = (U64*)(srt_c + 22616);

  const int hHW[5]    = {4096,1024,256,64,16};
  const int hLogHW[5] = {12,10,8,6,4};
  const int hLogW[5]  = {6,5,4,3,2};
  const int hW[5]     = {64,32,16,8,4};
  const int hPW[5]    = {66,34,18,10,6};
  const int hPS[5]    = {4356,1156,324,100,36};
  const int hPadOff[5]= {0,2230272,2822144,2988032,3039232};

  fill_zero4<<<2048, 256, 0, stream>>>((float4*)P, (int)(5*BUFSZ/4));

  for (int l = 0; l < 5; ++l) {
    const int n = 2*256*hHW[l];
    int g = (n + 255)/256; if (g > 2048) g = 2048;
    pad_one_p4<<<g, 256, 0, stream>>>(feat[l], P + hPadOff[l], n, hLogHW[l], hLogW[l],
                                      hW[l], hPW[l], hPS[l]);
  }

  auto runFused = [&](int i, const float* sc_, const float* sb_, float* dc_, float* db_) {
    transp_w<<<2304, 256, 0, stream>>>(cwp[i], wTc, 256, 256);
    transp_w<<<2304, 256, 0, stream>>>(bwp[i], wTb, 256, 256);
    conv_hidden_fused<<<dim3(24, 32), dim3(256), 0, stream>>>(
        sc_, sb_, dc_, db_, wTc, wTb, cbp[i], bbp[i]);
  };
  runFused(0, P,  P,  Ac, Ab);
  runFused(1, Ac, Ab, Bc, Bb);
  runFused(2, Bc, Bb, Ac, Ab);
  runFused(3, Ac, Ab, Bc, Bb);

  transp_w<<<6480, 256, 0, stream>>>(cwp[4], wTfc, 720, 720);
  transp_w<<<432, 256, 0, stream>>>(bwp[4], wTfb, 36, 48);
  conv_final_fused<<<dim3(48, 48), dim3(256), 0, stream>>>(
      Bc, Bb, clsm, boxm, wTfc, wTfb, cbp[4], bbp[4]);

  topk_init<<<1, 1024, 0, stream>>>(hist, state);
  for (int pass = 0; pass < 3; ++pass) {
    topk_hist<<<dim3(128, 10), dim3(256), 0, stream>>>(clsm, hist, state, pass);
    topk_scan<<<1, 256, 0, stream>>>(hist, state);
  }
  topk_compact<<<dim3(128, 10), dim3(256), 0, stream>>>(clsm, state, cbuf);
  topk_sort_store<<<10, 1024, 0, stream>>>(cbuf, state, cand_s, cand_c, sel);

  box_decode<<<10, 1024, 0, stream>>>(boxm, cand_s, sel, (float4*)cand_b);

  nms_sort<<<dim3(2), dim3(1024), 8192*sizeof(U64), stream>>>(
      cand_s, (const float4*)cand_b, cand_c, srt_s, (float4*)srt_b, srt_c);
  nms_greedy<<<dim3(2), dim3(1024), 0, stream>>>(
      srt_s, (const float4*)srt_b, srt_c, (float*)d_out);
}

// Round 18
// 2739.154 us; speedup vs baseline: 1.1048x; 1.1048x over previous
//
#include <hip/hip_runtime.h>
#include <math.h>

typedef unsigned long long U64;
#define CCAP 4096

__constant__ float cANCH[180] = {
  -18.0f,-8.0f,25.0f,15.0f, -23.7183f,-11.1191f,30.7183f,18.1191f, -30.9228f,-15.0488f,37.9228f,22.0488f,
  -12.0f,-12.0f,19.0f,19.0f, -16.1587f,-16.1587f,23.1587f,23.1587f, -21.3984f,-21.3984f,28.3984f,28.3984f,
  -8.0f,-20.0f,15.0f,27.0f, -11.1191f,-26.2381f,18.1191f,33.2381f, -15.0488f,-34.0976f,22.0488f,41.0976f,
  -38.0f,-16.0f,53.0f,31.0f, -49.9564f,-22.2381f,64.9564f,37.2381f, -65.0204f,-30.0976f,80.0204f,45.0976f,
  -24.0f,-24.0f,39.0f,39.0f, -32.3175f,-32.3175f,47.3175f,47.3175f, -42.7968f,-42.7968f,57.7968f,57.7968f,
  -14.0f,-36.0f,29.0f,51.0f, -19.7183f,-47.4365f,34.7183f,62.4365f, -26.9228f,-61.8456f,41.9228f,76.8456f,
  -74.0f,-28.0f,105.0f,59.0f, -97.3929f,-39.4365f,128.3929f,70.4365f, -126.8661f,-53.8456f,157.8661f,84.8456f,
  -48.0f,-48.0f,79.0f,79.0f, -64.6349f,-64.6349f,95.6349f,95.6349f, -85.5937f,-85.5937f,116.5937f,116.5937f,
  -30.0f,-76.0f,61.0f,107.0f, -41.9564f,-99.9127f,72.9564f,130.9127f, -57.0204f,-130.0409f,88.0204f,161.0409f,
  -150.0f,-60.0f,213.0f,123.0f, -197.3056f,-83.9127f,260.3056f,146.9127f, -256.907f,-114.0409f,319.907f,177.0409f,
  -96.0f,-96.0f,159.0f,159.0f, -129.2699f,-129.2699f,192.2699f,192.2699f, -171.1873f,-171.1873f,234.1873f,234.1873f,
  -58.0f,-148.0f,121.0f,211.0f, -81.3929f,-194.7858f,144.3929f,257.7858f, -110.8661f,-253.7322f,173.8661f,316.7322f,
  -298.0f,-116.0f,425.0f,243.0f, -392.0914f,-162.7858f,519.0914f,289.7858f, -510.6392f,-221.7322f,637.6392f,348.7322f,
  -192.0f,-192.0f,319.0f,319.0f, -258.5398f,-258.5398f,385.5398f,385.5398f, -342.3747f,-342.3747f,469.3747f,469.3747f,
  -118.0f,-300.0f,245.0f,427.0f, -165.3056f,-394.6113f,292.3056f,521.6113f, -224.907f,-513.814f,351.907f,640.814f
};

__device__ __constant__ int dH[5]      = {64,32,16,8,4};
__device__ __constant__ int dLogW[5]   = {6,5,4,3,2};
__device__ __constant__ int dHW[5]     = {4096,1024,256,64,16};
__device__ __constant__ int dPW[5]     = {66,34,18,10,6};
__device__ __constant__ int dPS[5]     = {4356,1156,324,100,36};
__device__ __constant__ int dPadOff[5] = {0,2230272,2822144,2988032,3039232};
__device__ __constant__ int dCO[5]     = {0,5898240,7372800,7741440,7833600};
__device__ __constant__ int dBO[5]     = {0,294912,368640,387072,391680};
__device__ __constant__ float dStrF[5] = {8.f,16.f,32.f,64.f,128.f};
// 256-pixel blocks (finals): counts 32,8,2,2,2 -> bases
__device__ __constant__ int dBase[6]   = {0,32,40,42,44,46};
__device__ __constant__ int dNPB[5]    = {16,4,1,1,1};
// 512-pixel blocks (hidden): counts 16,4,2,2,2 -> bases
__device__ __constant__ int dB2[6]   = {0,16,20,22,24,26};
__device__ __constant__ int dNPB2[5] = {8,2,1,1,1};

// ---------------- utility ----------------
__global__ void fill_zero4(float4* __restrict__ p, int n4) {
  for (int i = blockIdx.x*blockDim.x + threadIdx.x; i < n4; i += gridDim.x*blockDim.x)
    p[i] = make_float4(0.f,0.f,0.f,0.f);
}

// feat (B,256,H,W) -> channel-block-4 padded: P4[b][kq=c/4][vpix][c%4]
__global__ void pad_one_p4(const float* __restrict__ f, float* __restrict__ P,
                           int n, int logHW, int logW, int W, int PW, int PS) {
  const int HW1 = (1<<logHW) - 1;
  for (int i = blockIdx.x*blockDim.x + threadIdx.x; i < n; i += gridDim.x*blockDim.x) {
    const int bc = i >> logHW;
    const int p  = i & HW1;
    const int b = bc >> 8, c = bc & 255;
    const int y = p >> logW, x = p & (W-1);
    const int vpix = (y+1)*PW + (x+1);
    P[(((size_t)(b*64 + (c>>2)))*PS + vpix)*4 + (c&3)] = f[i];
  }
}

// w (Cout,256,3,3) -> wT[tap][k][ocP], zero padded ocs
__global__ void transp_w(const float* __restrict__ w, float* __restrict__ wT,
                         int Cout, int OCP) {
  const int n = 9*256*OCP;
  for (int i = blockIdx.x*blockDim.x + threadIdx.x; i < n; i += gridDim.x*blockDim.x) {
    const int oc = i % OCP;
    const int kt = i / OCP;
    const int k  = kt % 256;
    const int t  = kt / 256;
    wT[i] = (oc < Cout) ? w[(size_t)oc*2304 + k*9 + t] : 0.f;
  }
}

// 4 consecutive k rows x 16 ocs fed by one float4 (k ascending: x,y,z,w)
#define QUAD(KB, Q)                                                     \
  {                                                                     \
    const float* __restrict__ w0 = wp + (size_t)((KB)+0)*OCL;           \
    const float* __restrict__ w1 = wp + (size_t)((KB)+1)*OCL;           \
    const float* __restrict__ w2 = wp + (size_t)((KB)+2)*OCL;           \
    const float* __restrict__ w3 = wp + (size_t)((KB)+3)*OCL;           \
    _Pragma("unroll") for (int o=0;o<16;++o) acc[o]=fmaf(w0[o],(Q).x,acc[o]); \
    _Pragma("unroll") for (int o=0;o<16;++o) acc[o]=fmaf(w1[o],(Q).y,acc[o]); \
    _Pragma("unroll") for (int o=0;o<16;++o) acc[o]=fmaf(w2[o],(Q).z,acc[o]); \
    _Pragma("unroll") for (int o=0;o<16;++o) acc[o]=fmaf(w3[o],(Q).w,acc[o]); \
  }

// same, 2 pixels sharing weight rows
#define QUAD2(KB, QA, QB)                                               \
  {                                                                     \
    const float* __restrict__ w0 = wp + (size_t)((KB)+0)*OCL;           \
    const float* __restrict__ w1 = wp + (size_t)((KB)+1)*OCL;           \
    const float* __restrict__ w2 = wp + (size_t)((KB)+2)*OCL;           \
    const float* __restrict__ w3 = wp + (size_t)((KB)+3)*OCL;           \
    _Pragma("unroll") for (int o=0;o<16;++o) { acc0[o]=fmaf(w0[o],(QA).x,acc0[o]); acc1[o]=fmaf(w0[o],(QB).x,acc1[o]); } \
    _Pragma("unroll") for (int o=0;o<16;++o) { acc0[o]=fmaf(w1[o],(QA).y,acc0[o]); acc1[o]=fmaf(w1[o],(QB).y,acc1[o]); } \
    _Pragma("unroll") for (int o=0;o<16;++o) { acc0[o]=fmaf(w2[o],(QA).z,acc0[o]); acc1[o]=fmaf(w2[o],(QB).z,acc1[o]); } \
    _Pragma("unroll") for (int o=0;o<16;++o) { acc0[o]=fmaf(w3[o],(QA).w,acc0[o]); acc1[o]=fmaf(w3[o],(QB).w,acc1[o]); } \
  }

// ---------------- fused hidden conv (cls+box), 2 pixels/thread (round-15/16 winner) --------
__global__ __launch_bounds__(256)
void conv_hidden_fused(const float* __restrict__ srcC, const float* __restrict__ srcB,
                       float* __restrict__ dstC, float* __restrict__ dstB,
                       const float* __restrict__ wTc, const float* __restrict__ wTb,
                       const float* __restrict__ biasC, const float* __restrict__ biasB)
{
  const int OCL = 256;
  const int bx = blockIdx.x;
  if (bx >= 26) return;
  int l = 0;
  if (bx >= dB2[1]) l = 1;
  if (bx >= dB2[2]) l = 2;
  if (bx >= dB2[3]) l = 3;
  if (bx >= dB2[4]) l = 4;
  const int npb = dNPB2[l];
  const int rel = bx - dB2[l];
  const int b = rel / npb, pb = rel % npb;
  const int W = dH[l], logW = dLogW[l], HW = dHW[l], PW = dPW[l], PS = dPS[l];
  const int tid = threadIdx.x;
  const int pix0 = pb*512 + tid;
  const int pix1 = pix0 + 256;
  const bool a1 = pix1 < HW;
  if (pix0 >= HW) return;
  const int y0 = pix0 >> logW, x0 = pix0 & (W-1);
  const int y1 = pix1 >> logW, x1 = pix1 & (W-1);
  const int voff0 = (y0+1)*PW + (x0+1);
  const int voff1 = a1 ? (y1+1)*PW + (x1+1) : voff0;
  const int head = blockIdx.y >> 4;
  const float* __restrict__ IN  = head ? srcB : srcC;
  float* __restrict__ OUT       = head ? dstB : dstC;
  const float* __restrict__ wT  = head ? wTb : wTc;
  const float* __restrict__ bias= head ? biasB : biasC;
  const float4* __restrict__ P4 = (const float4*)(IN + dPadOff[l]);
  const float4* __restrict__ inB = P4 + (size_t)b*64*PS;
  const int oc0 = (blockIdx.y & 15) * 16;
  float acc0[16], acc1[16];
#pragma unroll
  for (int o = 0; o < 16; ++o) { acc0[o] = 0.f; acc1[o] = 0.f; }
#pragma unroll 1
  for (int t = 0; t < 9; ++t) {
    const int dy = t / 3, dx = t - dy * 3;
    const int sh = (dy-1)*PW + (dx-1);
    const float4* __restrict__ ipA = inB + (voff0 + sh);
    const float4* __restrict__ ipB = inB + (voff1 + sh);
    const float* __restrict__ wp = wT + (size_t)t*256*OCL + oc0;
#pragma unroll 1
    for (int k0 = 0; k0 < 256; k0 += 16) {
      const int kq = k0 >> 2;
      const float4 qa0 = ipA[(size_t)(kq+0)*PS];
      const float4 qb0 = ipB[(size_t)(kq+0)*PS];
      const float4 qa1 = ipA[(size_t)(kq+1)*PS];
      const float4 qb1 = ipB[(size_t)(kq+1)*PS];
      const float4 qa2 = ipA[(size_t)(kq+2)*PS];
      const float4 qb2 = ipB[(size_t)(kq+2)*PS];
      const float4 qa3 = ipA[(size_t)(kq+3)*PS];
      const float4 qb3 = ipB[(size_t)(kq+3)*PS];
      QUAD2(k0+ 0, qa0, qb0);
      QUAD2(k0+ 4, qa1, qb1);
      QUAD2(k0+ 8, qa2, qb2);
      QUAD2(k0+12, qa3, qb3);
    }
  }
  float4* __restrict__ O4 = (float4*)(OUT + dPadOff[l]);
  float4* __restrict__ opBase = O4 + ((size_t)b*64 + (oc0 >> 2))*PS;
#pragma unroll
  for (int j = 0; j < 4; ++j) {
    const float b0 = bias[oc0+4*j+0], b1 = bias[oc0+4*j+1];
    const float b2 = bias[oc0+4*j+2], b3 = bias[oc0+4*j+3];
    opBase[(size_t)j*PS + voff0] = make_float4(
      fmaxf(acc0[4*j+0] + b0, 0.f), fmaxf(acc0[4*j+1] + b1, 0.f),
      fmaxf(acc0[4*j+2] + b2, 0.f), fmaxf(acc0[4*j+3] + b3, 0.f));
    if (a1)
      opBase[(size_t)j*PS + voff1] = make_float4(
        fmaxf(acc1[4*j+0] + b0, 0.f), fmaxf(acc1[4*j+1] + b1, 0.f),
        fmaxf(acc1[4*j+2] + b2, 0.f), fmaxf(acc1[4*j+3] + b3, 0.f));
  }
}

// ---------------- fused finals, 1 pixel/thread (round-14/16 winner) ----------------
// grid = (48, 48): by<45 -> cls oc-block (sigmoid, Cout=720, OCL=720); else box (Cout=36, OCL=48)
__global__ __launch_bounds__(256)
void conv_final_fused(const float* __restrict__ srcC, const float* __restrict__ srcB,
                      float* __restrict__ clsm, float* __restrict__ boxm,
                      const float* __restrict__ wTfc, const float* __restrict__ wTfb,
                      const float* __restrict__ biasC, const float* __restrict__ biasB)
{
  const int bx = blockIdx.x;
  if (bx >= 46) return;
  int l = 0;
  if (bx >= dBase[1]) l = 1;
  if (bx >= dBase[2]) l = 2;
  if (bx >= dBase[3]) l = 3;
  if (bx >= dBase[4]) l = 4;
  const int npb = dNPB[l];
  const int rel = bx - dBase[l];
  const int b = rel / npb, pb = rel % npb;
  const int W = dH[l], logW = dLogW[l], HW = dHW[l], PW = dPW[l], PS = dPS[l];
  const int pix = pb*256 + threadIdx.x;
  if (pix >= HW) return;
  const bool isCls = blockIdx.y < 45;
  const int ocb = isCls ? blockIdx.y : (blockIdx.y - 45);
  const int OCL = isCls ? 720 : 48;
  const int Cout = isCls ? 720 : 36;
  const float* __restrict__ IN  = isCls ? srcC : srcB;
  const float* __restrict__ wT  = isCls ? wTfc : wTfb;
  const float* __restrict__ bias= isCls ? biasC : biasB;
  const int y = pix >> logW, x = pix & (W-1);
  const int voff = (y+1)*PW + (x+1);
  const float4* __restrict__ P4 = (const float4*)(IN + dPadOff[l]);
  const float4* __restrict__ inB = P4 + (size_t)b*64*PS + voff;
  const int oc0 = ocb * 16;
  float acc[16];
#pragma unroll
  for (int o = 0; o < 16; ++o) acc[o] = 0.f;
#pragma unroll 1
  for (int t = 0; t < 9; ++t) {
    const int dy = t / 3, dx = t - dy * 3;
    const float4* __restrict__ ip = inB + ((dy-1)*PW + (dx-1));
    const float* __restrict__ wp = wT + (size_t)t*256*OCL + oc0;
#pragma unroll 1
    for (int k0 = 0; k0 < 256; k0 += 16) {
      const int kq = k0 >> 2;
      const float4 q0 = ip[(size_t)(kq+0)*PS];
      const float4 q1 = ip[(size_t)(kq+1)*PS];
      const float4 q2 = ip[(size_t)(kq+2)*PS];
      const float4 q3 = ip[(size_t)(kq+3)*PS];
      QUAD(k0+ 0, q0);
      QUAD(k0+ 4, q1);
      QUAD(k0+ 8, q2);
      QUAD(k0+12, q3);
    }
  }
  const int outOff = isCls ? dCO[l] : dBO[l];
  float* __restrict__ OUT = isCls ? clsm : boxm;
#pragma unroll
  for (int o = 0; o < 16; ++o) {
    const int oc = oc0 + o;
    if (oc < Cout) {
      float tv = acc[o] + bias[oc];
      if (isCls) tv = 1.f / (1.f + expf(-tv));
      OUT[(size_t)outOff + ((size_t)b*Cout + oc)*HW + pix] = tv;
    }
  }
}

// ---------------- exact top-1000 per (batch,level) ----------------
__global__ void topk_init(unsigned* __restrict__ hist, unsigned* __restrict__ state) {
  for (int i = threadIdx.x; i < 2560; i += blockDim.x) hist[i] = 0u;
  if (threadIdx.x < 10) {
    state[threadIdx.x*4+0] = 0u; state[threadIdx.x*4+1] = 1000u;
    state[threadIdx.x*4+2] = 0u; state[threadIdx.x*4+3] = 0u;
  }
}

__global__ void topk_hist(const float* __restrict__ clsm, unsigned* __restrict__ hist,
                          const unsigned* __restrict__ state, int pass)
{
  __shared__ unsigned lh[256];
  const int id = blockIdx.y, l = id % 5, b = id / 5;
  const int N = 720 * dHW[l];
  const float* __restrict__ sp = clsm + dCO[l] + (size_t)b*720*dHW[l];
  for (int i = threadIdx.x; i < 256; i += blockDim.x) lh[i] = 0u;
  __syncthreads();
  const unsigned prefix = state[id*4];
  for (int i = blockIdx.x*blockDim.x + threadIdx.x; i < N; i += gridDim.x*blockDim.x) {
    const unsigned bits = __float_as_uint(sp[i]);
    unsigned bin; bool ok;
    if (pass == 0)      { bin = bits >> 24;          ok = true; }
    else if (pass == 1) { bin = (bits >> 16) & 0xFF; ok = ((bits >> 24) == prefix); }
    else                { bin = (bits >>  8) & 0xFF; ok = ((bits >> 16) == prefix); }
    if (ok) atomicAdd(&lh[bin], 1u);
  }
  __syncthreads();
  for (int i = threadIdx.x; i < 256; i += blockDim.x)
    if (lh[i]) atomicAdd(&hist[id*256 + i], lh[i]);
}

__global__ void topk_scan(unsigned* __restrict__ hist, unsigned* __restrict__ state) {
  const int id = threadIdx.x;
  if (id < 10) {
    const unsigned k = state[id*4+1];
    unsigned cum = 0; int d = 255;
    for (; d > 0; --d) {
      const unsigned h = hist[id*256 + d];
      if (cum + h >= k) break;
      cum += h;
    }
    state[id*4+0] = (state[id*4+0] << 8) | (unsigned)d;
    state[id*4+1] = k - cum;
  }
  __syncthreads();
  for (int i = threadIdx.x; i < 2560; i += blockDim.x) hist[i] = 0u;
}

__global__ void topk_compact(const float* __restrict__ clsm, unsigned* __restrict__ state,
                             U64* __restrict__ cbuf)
{
  const int id = blockIdx.y, l = id % 5, b = id / 5;
  const int N = 720 * dHW[l];
  const float* __restrict__ sp = clsm + dCO[l] + (size_t)b*720*dHW[l];
  const unsigned p24 = state[id*4];
  for (int i = blockIdx.x*blockDim.x + threadIdx.x; i < N; i += gridDim.x*blockDim.x) {
    const unsigned bits = __float_as_uint(sp[i]);
    if ((bits >> 8) >= p24) {
      const unsigned pos = atomicAdd(&state[id*4+2], 1u);
      if (pos < CCAP)
        cbuf[(size_t)id*CCAP + pos] = ((U64)bits << 32) | (U64)(0xFFFFFFFFu - (unsigned)i);
    }
  }
}

__global__ __launch_bounds__(1024)
void topk_sort_store(const U64* __restrict__ cbuf, const unsigned* __restrict__ state,
                     float* __restrict__ cand_s, float* __restrict__ cand_c,
                     unsigned* __restrict__ sel)
{
  __shared__ U64 sk[CCAP];
  const int id = blockIdx.x, l = id % 5, b = id / 5;
  const int t = threadIdx.x;
  unsigned M = state[id*4+2]; if (M > (unsigned)CCAP) M = CCAP;
  for (int i = t; i < CCAP; i += 1024) sk[i] = (i < (int)M) ? cbuf[(size_t)id*CCAP + i] : 0ull;
  __syncthreads();
  for (int k = 2; k <= CCAP; k <<= 1)
    for (int j = k >> 1; j > 0; j >>= 1) {
      for (int u = t; u < CCAP/2; u += 1024) {
        const int i1 = ((u & ~(j-1)) << 1) | (u & (j-1));
        const int i2 = i1 + j;
        const bool asc = ((i1 & k) == 0);
        const U64 a = sk[i1], c = sk[i2];
        if ((a < c) == asc) { sk[i1] = c; sk[i2] = a; }
      }
      __syncthreads();
    }
  const int HW = dHW[l];
  for (int j = t; j < 1000; j += 1024) {
    float sc_ = 0.f, cf = 0.f; unsigned sidx = 0xFFFFFFFFu;
    if (j < (int)M) {
      const U64 key = sk[j];
      const float s = __uint_as_float((unsigned)(key >> 32));
      const unsigned idx = 0xFFFFFFFFu - (unsigned)key;
      if (s >= 0.05f) {
        const int ch = (int)(idx / (unsigned)HW);
        const int cls = ch % 80;
        sc_ = s; cf = (float)cls; sidx = idx;
      }
    }
    const int slot = b*5000 + l*1000 + j;
    cand_s[slot] = sc_; cand_c[slot] = cf; sel[slot] = sidx;
  }
}

__global__ __launch_bounds__(1024)
void box_decode(const float* __restrict__ boxm, const float* __restrict__ cand_s,
                const unsigned* __restrict__ sel, float4* __restrict__ cand_b)
{
  const int id = blockIdx.x, l = id % 5, b = id / 5;
  const int HW = dHW[l], W = dH[l], logW = dLogW[l];
  const float stride = dStrF[l];
  const int j = threadIdx.x;
  if (j >= 1000) return;
  const int slot = b*5000 + l*1000 + j;
  float4 bx = make_float4(0.f,0.f,0.f,0.f);
  if (cand_s[slot] > 0.f) {
    const unsigned idx = sel[slot];
    const int pix = (int)(idx & (unsigned)(HW-1));
    const int ch  = (int)(idx >> (2*logW));
    const int a   = ch / 80;
    const int xx = pix & (W-1), yy = pix >> logW;
    const float* __restrict__ bm = boxm + dBO[l] + (size_t)b*36*HW;
    const float d0 = bm[(size_t)(a*4+0)*HW + pix];
    const float d1 = bm[(size_t)(a*4+1)*HW + pix];
    const float d2 = bm[(size_t)(a*4+2)*HW + pix];
    const float d3 = bm[(size_t)(a*4+3)*HW + pix];
    const float* A = &cANCH[l*36 + a*4];
    const float g0 = (float)xx * stride + A[0];
    const float g1 = (float)yy * stride + A[1];
    const float g2 = (float)xx * stride + A[2];
    const float g3 = (float)yy * stride + A[3];
    const float awx = g2 - g0 + 1.f, awy = g3 - g1 + 1.f;
    const float cx = g0 + 0.5f*awx, cy = g1 + 0.5f*awy;
    const float pcx = d0*awx + cx, pcy = d1*awy + cy;
    const float pwx = expf(d2)*awx, pwy = expf(d3)*awy;
    const float Mx = (float)W*stride - 1.f, My = (float)W*stride - 1.f;
    const float x1 = fminf(fmaxf(pcx - 0.5f*pwx, 0.f), Mx);
    const float y1 = fminf(fmaxf(pcy - 0.5f*pwy, 0.f), My);
    const float x2 = fminf(fmaxf(pcx + 0.5f*pwx - 1.f, 0.f), Mx);
    const float y2 = fminf(fmaxf(pcy + 0.5f*pwy - 1.f, 0.f), My);
    bx = make_float4(x1, y1, x2, y2);
  }
  cand_b[slot] = bx;
}

// ---------------- NMS ----------------
__global__ __launch_bounds__(1024)
void nms_sort(const float* __restrict__ cs, const float4* __restrict__ cb, const float* __restrict__ cc,
              float* __restrict__ ss, float4* __restrict__ sb, float* __restrict__ sc)
{
  extern __shared__ U64 sk[];
  const int b = blockIdx.x;
  const int t = threadIdx.x;
  for (int i = t; i < 8192; i += 1024) {
    U64 key = 0ull;
    if (i < 5000) {
      const unsigned bits = __float_as_uint(cs[b*5000 + i]);
      key = ((U64)bits << 32) | (U64)(0xFFFFFFFFu - (unsigned)i);
    }
    sk[i] = key;
  }
  __syncthreads();
  for (int k = 2; k <= 8192; k <<= 1)
    for (int j = k >> 1; j > 0; j >>= 1) {
      for (int u = t; u < 4096; u += 1024) {
        const int i1 = ((u & ~(j-1)) << 1) | (u & (j-1));
        const int i2 = i1 + j;
        const bool asc = ((i1 & k) == 0);
        const U64 a = sk[i1], c = sk[i2];
        if ((a < c) == asc) { sk[i1] = c; sk[i2] = a; }
      }
      __syncthreads();
    }
  for (int i = t; i < 5000; i += 1024) {
    const unsigned pos = 0xFFFFFFFFu - (unsigned)sk[i];
    ss[b*5008 + i] = cs[b*5000 + pos];
    sb[b*5008 + i] = cb[b*5000 + pos];
    sc[b*5008 + i] = cc[b*5000 + pos];
  }
}

__global__ __launch_bounds__(1024)
void nms_greedy(const float* __restrict__ ss, const float4* __restrict__ sb, const float* __restrict__ sc,
                float* __restrict__ outp)
{
  const int b = blockIdx.x;
  const int t = threadIdx.x;
  __shared__ int red[16];
  __shared__ int selSh;
  __shared__ float bc[8];

  const float* SS = ss + (size_t)b*5008;
  const float4* SB = sb + (size_t)b*5008;
  const float* SC = sc + (size_t)b*5008;

  float s[5], c[5], ar[5]; float4 bx[5]; bool val[5];
#pragma unroll
  for (int k = 0; k < 5; ++k) {
    const int j = t + k*1024;
    if (j < 5000) {
      s[k] = SS[j]; c[k] = SC[j]; bx[k] = SB[j];
      val[k] = (s[k] > 0.f);
      ar[k] = (bx[k].z - bx[k].x + 1.f) * (bx[k].w - bx[k].y + 1.f);
    } else {
      s[k] = 0.f; c[k] = 0.f; bx[k] = make_float4(0.f,0.f,0.f,0.f);
      val[k] = false; ar[k] = 1.f;
    }
  }

  for (int i = 0; i < 100; ++i) {
    int loc = 0x7FFFFFFF;
#pragma unroll
    for (int k = 0; k < 5; ++k) if (val[k]) { const int j = t + k*1024; loc = (j < loc) ? j : loc; }
    for (int off = 32; off > 0; off >>= 1) { const int o = __shfl_down(loc, off); loc = (o < loc) ? o : loc; }
    if ((t & 63) == 0) red[t >> 6] = loc;
    __syncthreads();
    if (t < 64) {
      int v = (t < 16) ? red[t] : 0x7FFFFFFF;
      for (int off = 8; off > 0; off >>= 1) { const int o = __shfl_down(v, off); v = (o < v) ? o : v; }
      if (t == 0) selSh = v;
    }
    __syncthreads();
    const int sel_ = selSh;
    if (sel_ == 0x7FFFFFFF) {
      if (t == 0) {
        outp[b*100 + i] = 0.f;
        outp[200 + (b*100 + i)*4 + 0] = 0.f;
        outp[200 + (b*100 + i)*4 + 1] = 0.f;
        outp[200 + (b*100 + i)*4 + 2] = 0.f;
        outp[200 + (b*100 + i)*4 + 3] = 0.f;
        outp[1000 + b*100 + i] = 0.f;
      }
    } else {
      if (t == (sel_ & 1023)) {
        const int k = sel_ >> 10;
        bc[0] = s[k]; bc[1] = c[k];
        bc[2] = bx[k].x; bc[3] = bx[k].y; bc[4] = bx[k].z; bc[5] = bx[k].w;
        bc[6] = ar[k];
        outp[b*100 + i] = s[k];
        outp[200 + (b*100 + i)*4 + 0] = bx[k].x;
        outp[200 + (b*100 + i)*4 + 1] = bx[k].y;
        outp[200 + (b*100 + i)*4 + 2] = bx[k].z;
        outp[200 + (b*100 + i)*4 + 3] = bx[k].w;
        outp[1000 + b*100 + i] = c[k];
      }
      __syncthreads();
      const float si = bc[0], ci = bc[1], ai = bc[6];
      const float bix = bc[2], biy = bc[3], biz = bc[4], biw = bc[5];
#pragma unroll
      for (int k = 0; k < 5; ++k) {
        if (!val[k]) continue;
        const float xx1 = fmaxf(bx[k].x, bix), yy1 = fmaxf(bx[k].y, biy);
        const float xx2 = fminf(bx[k].z, biz), yy2 = fminf(bx[k].w, biw);
        const float iw = fmaxf(xx2 - xx1 + 1.f, 0.f), ih = fmaxf(yy2 - yy1 + 1.f, 0.f);
        const float inter = iw * ih;
        const float iou = inter / (ar[k] + ai - inter);
        if (s[k] <= si && iou > 0.5f && c[k] == ci) val[k] = false;
      }
    }
    __syncthreads();
  }
}

// ---------------- host ----------------
extern "C" void kernel_launch(void* const* d_in, const int* in_sizes, int n_in,
                              void* d_out, int out_size, void* d_ws, size_t ws_size,
                              hipStream_t stream)
{
  (void)in_sizes; (void)n_in; (void)out_size; (void)ws_size;
  const float* feat[5]; const float* cwp[5]; const float* cbp[5]; const float* bwp[5]; const float* bbp[5];
  for (int i = 0; i < 5; ++i) feat[i] = (const float*)d_in[i];
  for (int i = 0; i < 5; ++i) {
    cwp[i] = (const float*)d_in[5 + 4*i + 0];
    cbp[i] = (const float*)d_in[5 + 4*i + 1];
    bwp[i] = (const float*)d_in[5 + 4*i + 2];
    bbp[i] = (const float*)d_in[5 + 4*i + 3];
  }

  float* ws = (float*)d_ws;
  const size_t BUFSZ = 3057664;
  float* P     = ws;
  float* Ac    = ws + BUFSZ;
  float* Bc    = ws + 2*BUFSZ;
  float* Ab    = ws + 3*BUFSZ;
  float* Bb    = ws + 4*BUFSZ;
  float* clsm  = ws + 5*BUFSZ;
  float* boxm  = clsm + 7856640;
  float* wreg  = boxm + 392832;
  float* wTc   = wreg;
  float* wTb   = wreg + 589824;
  float* wTfc  = wreg;
  float* wTfb  = wreg + 1658880;
  float* cand_s = wreg + 1769472;
  float* cand_b = cand_s + 10000;
  float* cand_c = cand_b + 40000;
  float* srt_s  = cand_c + 10000;
  float* srt_b  = srt_s + 10016;
  float* srt_c  = srt_b + 40064;
  unsigned* sel   = (unsigned*)(srt_c + 10016);
  unsigned* hist  = (unsigned*)(srt_c + 20016);
  unsigned* state = (unsigned*)(srt_c + 22576);
  U64*      cbuf  = (U64*)(srt_c + 22616);

  const int hHW[5]    = {4096,1024,256,64,16};
  const int hLogHW[5] = {12,10,8,6,4};
  const int hLogW[5]  = {6,5,4,3,2};
  const int hW[5]     = {64,32,16,8,4};
  const int hPW[5]    = {66,34,18,10,6};
  const int hPS[5]    = {4356,1156,324,100,36};
  const int hPadOff[5]= {0,2230272,2822144,2988032,3039232};

  fill_zero4<<<2048, 256, 0, stream>>>((float4*)P, (int)(5*BUFSZ/4));

  for (int l = 0; l < 5; ++l) {
    const int n = 2*256*hHW[l];
    int g = (n + 255)/256; if (g > 2048) g = 2048;
    pad_one_p4<<<g, 256, 0, stream>>>(feat[l], P + hPadOff[l], n, hLogHW[l], hLogW[l],
                                      hW[l], hPW[l], hPS[l]);
  }

  auto runFused = [&](int i, const float* sc_, const float* sb_, float* dc_, float* db_) {
    transp_w<<<2304, 256, 0, stream>>>(cwp[i], wTc, 256, 256);
    transp_w<<<2304, 256, 0, stream>>>(bwp[i], wTb, 256, 256);
    conv_hidden_fused<<<dim3(32, 32), dim3(256), 0, stream>>>(
        sc_, sb_, dc_, db_, wTc, wTb, cbp[i], bbp[i]);
  };
  runFused(0, P,  P,  Ac, Ab);
  runFused(1, Ac, Ab, Bc, Bb);
  runFused(2, Bc, Bb, Ac, Ab);
  runFused(3, Ac, Ab, Bc, Bb);

  transp_w<<<6480, 256, 0, stream>>>(cwp[4], wTfc, 720, 720);
  transp_w<<<432, 256, 0, stream>>>(bwp[4], wTfb, 36, 48);
  conv_final_fused<<<dim3(48, 48), dim3(256), 0, stream>>>(
      Bc, Bb, clsm, boxm, wTfc, wTfb, cbp[4], bbp[4]);

  topk_init<<<1, 1024, 0, stream>>>(hist, state);
  for (int pass = 0; pass < 3; ++pass) {
    topk_hist<<<dim3(128, 10), dim3(256), 0, stream>>>(clsm, hist, state, pass);
    topk_scan<<<1, 256, 0, stream>>>(hist, state);
  }
  topk_compact<<<dim3(128, 10), dim3(256), 0, stream>>>(clsm, state, cbuf);
  topk_sort_store<<<10, 1024, 0, stream>>>(cbuf, state, cand_s, cand_c, sel);

  box_decode<<<10, 1024, 0, stream>>>(boxm, cand_s, sel, (float4*)cand_b);

  nms_sort<<<dim3(2), dim3(1024), 8192*sizeof(U64), stream>>>(
      cand_s, (const float4*)cand_b, cand_c, srt_s, (float4*)srt_b, srt_c);
  nms_greedy<<<dim3(2), dim3(1024), 0, stream>>>(
      srt_s, (const float4*)srt_b, srt_c, (float*)d_out);
}